// Round 3
// baseline (1879.520 us; speedup 1.0000x reference)
//
#include <hip/hip_runtime.h>
#include <math.h>

#define D_DIM 256
#define K_CB  1024
#define EPS   1e-8f

typedef _Float16 half4_t __attribute__((ext_vector_type(4)));
typedef _Float16 half8_t __attribute__((ext_vector_type(8)));
typedef float    f32x4   __attribute__((ext_vector_type(4)));

// Split fp32 -> hi fp16 + lo fp16 (lo pre-scaled by 2^11 so it stays in fp16
// normal range; true value = hi + lo * 2^-11, residual ~2^-23 relative).
__device__ __forceinline__ void split2(const float4 v, half4_t& h, half4_t& l)
{
    h[0] = (_Float16)v.x; h[1] = (_Float16)v.y;
    h[2] = (_Float16)v.z; h[3] = (_Float16)v.w;
    l[0] = (_Float16)((v.x - (float)h[0]) * 2048.0f);
    l[1] = (_Float16)((v.y - (float)h[1]) * 2048.0f);
    l[2] = (_Float16)((v.z - (float)h[2]) * 2048.0f);
    l[3] = (_Float16)((v.w - (float)h[3]) * 2048.0f);
}

// ws layout (floats): [0, N) latent scales = 1/(max(||a||,eps)*temp)
// then b0img (512 KB), b1img (512 KB): pre-normalized split codebook,
// frag-major: half8 index = s*1024 + g*256 + col  (s = stage = ct*8+ds,
// holding d in [ds*32 + g*8, +8), col = column within the ct 256-tile).
__global__ __launch_bounds__(256) void qnorms_kernel(
    const float* __restrict__ latent,
    const float* __restrict__ temp,
    float* __restrict__ scales,
    int N)
{
    const int w = blockIdx.x * 4 + (threadIdx.x >> 6);   // one wave per row
    const int lane = threadIdx.x & 63;
    if (w >= N) return;
    float4 v = reinterpret_cast<const float4*>(latent + (size_t)w * D_DIM)[lane];
    float ss = v.x * v.x + v.y * v.y + v.z * v.z + v.w * v.w;
#pragma unroll
    for (int off = 32; off > 0; off >>= 1) ss += __shfl_down(ss, off, 64);
    if (lane == 0)
        scales[w] = 1.0f / (fmaxf(sqrtf(ss), EPS) * temp[0]);
}

// One wave per codebook row: normalize (fold 1/||b||), split, scatter into
// the frag-major image so qmain's B loads are plain 16B L2 reads.
__global__ __launch_bounds__(256) void cbsplit_kernel(
    const float* __restrict__ codebook,
    _Float16* __restrict__ b0img,
    _Float16* __restrict__ b1img)
{
    const int k    = blockIdx.x * 4 + (threadIdx.x >> 6);  // codebook row (= col)
    const int lane = threadIdx.x & 63;
    float4 v = reinterpret_cast<const float4*>(codebook + (size_t)k * D_DIM)[lane];
    float ss = v.x * v.x + v.y * v.y + v.z * v.z + v.w * v.w;
#pragma unroll
    for (int off = 1; off < 64; off <<= 1) ss += __shfl_xor(ss, off, 64);
    const float inv = 1.0f / fmaxf(sqrtf(ss), EPS);
    v.x *= inv; v.y *= inv; v.z *= inv; v.w *= inv;
    half4_t h0, h1; split2(v, h0, h1);

    const int d  = lane * 4;
    const int ct = k >> 8, cl = k & 255;
    const int s  = ct * 8 + (d >> 5);
    const int g  = (d >> 3) & 3;
    const size_t ha = ((size_t)(s * 4 + g) * 256 + cl) * 8 + (d & 7);
    *reinterpret_cast<half4_t*>(b0img + ha) = h0;
    *reinterpret_cast<half4_t*>(b1img + ha) = h1;
}

// MFMA main kernel. 256 threads = 4 waves, 64 rows/block, wave grid 1x4:
// wave wc owns cols wc*64 + t*16 (t=0..3), rt=0..3 covers all 64 rows.
// A (pre-scaled by 1/(||a|| temp), split fp16) resident in LDS, swizzled.
// B frags loaded directly from the pre-split L2-resident image: NO B LDS,
// NO per-stage barriers - the K-loop is free-running.
__global__ __launch_bounds__(256, 2) void qmain_kernel(
    const float* __restrict__ latent,
    const float* __restrict__ noise,
    const float* __restrict__ codebook,
    const float* __restrict__ scales,
    const _Float16* __restrict__ b0img,
    const _Float16* __restrict__ b1img,
    float* __restrict__ out,
    int N)
{
    __shared__ __align__(16) _Float16 A0s[64 * 256];   // 32 KB
    __shared__ __align__(16) _Float16 A1s[64 * 256];   // 32 KB
    __shared__ float scale_s[64];
    __shared__ float vmax_s[4][64];
    __shared__ int   vidx_s[4][64];
    __shared__ int   idx_s[64];

    const int tid  = threadIdx.x;
    const int row0 = blockIdx.x * 64;
    const int wc   = tid >> 6;     // wave = col quarter
    const int lane = tid & 63;
    const int c16  = lane & 15;
    const int g    = lane >> 4;

    if (tid < 64) scale_s[tid] = scales[row0 + tid];
    __syncthreads();

    // ---- Stage A (64 x 256 fp32) -> pre-scaled split fp16 LDS, swizzled ----
    {
        const int f4   = tid & 63;         // d0 = f4*4
        const int rsub = tid >> 6;
        const int d0   = f4 * 4;
#pragma unroll
        for (int p = 0; p < 16; ++p) {
            const int row = p * 4 + rsub;
            float4 v = reinterpret_cast<const float4*>(
                latent + (size_t)(row0 + row) * D_DIM)[f4];
            const float sc = scale_s[row];
            v.x *= sc; v.y *= sc; v.z *= sc; v.w *= sc;
            half4_t h0, h1; split2(v, h0, h1);
            const int idx = row * 256 + (d0 ^ ((row & 7) << 3));
            *reinterpret_cast<half4_t*>(&A0s[idx]) = h0;
            *reinterpret_cast<half4_t*>(&A1s[idx]) = h1;
        }
    }
    __syncthreads();

    float rmax[4][4];
    int   ridx[4][4];
#pragma unroll
    for (int rt = 0; rt < 4; ++rt)
#pragma unroll
        for (int j = 0; j < 4; ++j) { rmax[rt][j] = -INFINITY; ridx[rt][j] = 0x7fffffff; }

    const int boff8 = g * 256 + wc * 64 + c16;   // per-lane half8 offset in stage image

    for (int ct = 0; ct < 4; ++ct) {
        f32x4 acc_hi[4][4], acc_mid[4][4];
#pragma unroll
        for (int rt = 0; rt < 4; ++rt)
#pragma unroll
            for (int t = 0; t < 4; ++t) {
                acc_hi[rt][t]  = (f32x4){0.f, 0.f, 0.f, 0.f};
                acc_mid[rt][t] = (f32x4){0.f, 0.f, 0.f, 0.f};
            }

        for (int ds = 0; ds < 8; ++ds) {
            const int s = ct * 8 + ds;
            const _Float16* bp0 = b0img + (size_t)s * 8192;
            const _Float16* bp1 = b1img + (size_t)s * 8192;

            half8_t bh[4], bl[4];
#pragma unroll
            for (int t = 0; t < 4; ++t) {
                bh[t] = *reinterpret_cast<const half8_t*>(bp0 + (size_t)(boff8 + t * 16) * 8);
                bl[t] = *reinterpret_cast<const half8_t*>(bp1 + (size_t)(boff8 + t * 16) * 8);
            }

            const int dA = ds * 32 + g * 8;
            half8_t a0[4], a1[4];
#pragma unroll
            for (int rt = 0; rt < 4; ++rt) {
                const int arow = rt * 16 + c16;
                const int aidx = arow * 256 + (dA ^ ((arow & 7) << 3));
                a0[rt] = *reinterpret_cast<const half8_t*>(&A0s[aidx]);
                a1[rt] = *reinterpret_cast<const half8_t*>(&A1s[aidx]);
            }
#pragma unroll
            for (int t = 0; t < 4; ++t)
#pragma unroll
                for (int rt = 0; rt < 4; ++rt) {
                    acc_hi[rt][t]  = __builtin_amdgcn_mfma_f32_16x16x32_f16(
                        a0[rt], bh[t], acc_hi[rt][t], 0, 0, 0);
                    acc_mid[rt][t] = __builtin_amdgcn_mfma_f32_16x16x32_f16(
                        a1[rt], bh[t], acc_mid[rt][t], 0, 0, 0);
                    acc_mid[rt][t] = __builtin_amdgcn_mfma_f32_16x16x32_f16(
                        a0[rt], bl[t], acc_mid[rt][t], 0, 0, 0);
                }
        }

        // ---- epilogue for this 256-col tile: gumbel + running argmax ----
#pragma unroll
        for (int rt = 0; rt < 4; ++rt) {
#pragma unroll
            for (int j = 0; j < 4; ++j) {
                const int rowg = row0 + rt * 16 + g * 4 + j;
                const float* nrow = noise + (size_t)rowg * K_CB + ct * 256;
                float v  = rmax[rt][j];
                int   vi = ridx[rt][j];
#pragma unroll
                for (int t = 0; t < 4; ++t) {
                    const int cloc = wc * 64 + t * 16 + c16;
                    const float u   = nrow[cloc];
                    const float gum = -logf(-logf(u));
                    const float l   = acc_hi[rt][t][j]
                                    + acc_mid[rt][t][j] * (1.0f / 2048.0f) + gum;
                    const int cidx = ct * 256 + cloc;
                    if (l > v || (l == v && cidx < vi)) { v = l; vi = cidx; }
                }
                rmax[rt][j] = v;
                ridx[rt][j] = vi;
            }
        }
    }

    // ---- reduce across the 16 lanes sharing each row, then across waves ----
#pragma unroll
    for (int rt = 0; rt < 4; ++rt)
#pragma unroll
        for (int j = 0; j < 4; ++j) {
            float v  = rmax[rt][j];
            int   vi = ridx[rt][j];
#pragma unroll
            for (int off = 1; off < 16; off <<= 1) {
                const float ov = __shfl_xor(v, off, 16);
                const int   oi = __shfl_xor(vi, off, 16);
                if (ov > v || (ov == v && oi < vi)) { v = ov; vi = oi; }
            }
            if (c16 == 0) {
                const int rloc = rt * 16 + g * 4 + j;
                vmax_s[wc][rloc] = v;
                vidx_s[wc][rloc] = vi;
            }
        }
    __syncthreads();
    if (tid < 64) {
        float v = vmax_s[0][tid]; int vi = vidx_s[0][tid];
#pragma unroll
        for (int w = 1; w < 4; ++w) {
            const float ov = vmax_s[w][tid];
            const int   oi = vidx_s[w][tid];
            if (ov > v || (ov == v && oi < vi)) { v = ov; vi = oi; }
        }
        idx_s[tid] = vi;
    }
    __syncthreads();

    // ---- gather: out[row] = codebook[idx[row]] (coalesced 1KB per row) ----
    {
        const int l2 = tid & 63;
        const int rr = tid >> 6;
#pragma unroll
        for (int p = 0; p < 16; ++p) {
            const int row = rr * 16 + p;
            const int idx = idx_s[row];
            const float4 v =
                reinterpret_cast<const float4*>(codebook + (size_t)idx * D_DIM)[l2];
            reinterpret_cast<float4*>(out + (size_t)(row0 + row) * D_DIM)[l2] = v;
        }
    }
}

extern "C" void kernel_launch(void* const* d_in, const int* in_sizes, int n_in,
                              void* d_out, int out_size, void* d_ws, size_t ws_size,
                              hipStream_t stream)
{
    const float* latent   = (const float*)d_in[0];
    const float* noise    = (const float*)d_in[1];
    const float* codebook = (const float*)d_in[2];
    const float* temp     = (const float*)d_in[3];
    float* out    = (float*)d_out;
    float* scales = (float*)d_ws;                          // N floats
    const int N = in_sizes[0] / D_DIM;                     // 131072
    _Float16* b0img = (_Float16*)(scales + N);             // 512 KB
    _Float16* b1img = b0img + 32 * 8192;                   // 512 KB

    qnorms_kernel<<<(N + 3) / 4, 256, 0, stream>>>(latent, temp, scales, N);
    cbsplit_kernel<<<K_CB / 4, 256, 0, stream>>>(codebook, b0img, b1img);
    qmain_kernel<<<N / 64, 256, 0, stream>>>(latent, noise, codebook, scales,
                                             b0img, b1img, out, N);
}